// Round 1
// baseline (505.735 us; speedup 1.0000x reference)
//
#include <hip/hip_runtime.h>
#include <math.h>

typedef short v8s __attribute__((ext_vector_type(8)));
typedef float v4f __attribute__((ext_vector_type(4)));

#define EPS 1e-5f

__device__ __forceinline__ unsigned short f2bf(float x){
  unsigned u = __float_as_uint(x);
  return (unsigned short)((u + 0x7fffu + ((u>>16)&1u)) >> 16);
}
__device__ __forceinline__ float bf2f(unsigned short us){
  return __uint_as_float(((unsigned)us)<<16);
}

// ---------------------------------------------------------------------------
// K0: prep — G = W2 W2^T/768 (bf16), w2bar, u = W2 b2/768, b2bar, c0, W2T(bf16)
// grid: 64 (G rows) + 1 (stats) + 48 (transpose) = 113 blocks x 256
// ---------------------------------------------------------------------------
__global__ __launch_bounds__(256) void k_prep(const float* __restrict__ W2,
                                              const float* __restrict__ b2,
                                              unsigned short* __restrict__ Gm,
                                              float* __restrict__ w2bar,
                                              float* __restrict__ ubar,
                                              float* __restrict__ scal,
                                              unsigned short* __restrict__ W2T)
{
  __shared__ float row[768];
  __shared__ float part[256];
  int t = threadIdx.x;
  int blk = blockIdx.x;
  if (blk < 64){
    for (int c = t; c < 768; c += 256) row[c] = W2[blk*768 + c];
    __syncthreads();
    int jp = t & 63, quarter = t >> 6;
    float acc = 0.f;
    int c0 = quarter*192;
    for (int c = c0; c < c0+192; ++c) acc += row[c]*W2[jp*768 + c];
    part[t] = acc;
    __syncthreads();
    if (t < 64){
      float sv = part[t] + part[t+64] + part[t+128] + part[t+192];
      Gm[blk*64 + t] = f2bf(sv * (1.f/768.f));
    }
  } else if (blk == 64){
    if (t < 64){
      float sw=0.f, sus=0.f;
      for (int c=0;c<768;++c){ float wv=W2[t*768+c]; sw+=wv; sus+=wv*b2[c]; }
      w2bar[t]=sw*(1.f/768.f); ubar[t]=sus*(1.f/768.f);
    } else if (t == 64){
      float sb=0.f, sb2=0.f;
      for (int c=0;c<768;++c){ float v=b2[c]; sb+=v; sb2+=v*v; }
      scal[0]=sb*(1.f/768.f); scal[1]=sb2*(1.f/768.f);
    }
  } else {
    int bi = blk - 65;
    int c0 = bi*16;
    for (int idx = t; idx < 1024; idx += 256){
      int c = c0 + (idx >> 6), j = idx & 63;
      W2T[c*64 + j] = f2bf(W2[j*768 + c]);
    }
  }
}

// ---------------------------------------------------------------------------
// K1: exact KNN (top-9 by (d2, idx) lex, matching jax.lax.top_k ties) + geom
// grid: B*64 = 256 blocks x 1024 threads. thread = (query in 64, chunk in 16)
// ---------------------------------------------------------------------------
__global__ __launch_bounds__(1024) void k_knn(const float* __restrict__ coords,
                                              float* __restrict__ geom)
{
#pragma clang fp contract(off)
  __shared__ float cx[4096], cy[4096], cz[4096];
  __shared__ float md[64*16*9];
  __shared__ int   mi[64*16*9];
  __shared__ int   pcs[64*16];
  int t = threadIdx.x;
  int b  = blockIdx.x >> 6;
  int qb = blockIdx.x & 63;
  const float* cb = coords + (size_t)b*4096*3;
  for (int n = t; n < 4096; n += 1024){
    cx[n] = cb[n*3+0]; cy[n] = cb[n*3+1]; cz[n] = cb[n*3+2];
  }
  __syncthreads();
  int ql = t & 63, chunk = t >> 6;
  int nq = qb*64 + ql;
  float qx = cx[nq], qy = cy[nq], qz = cz[nq];
  float ld[9]; int li[9];
  #pragma unroll
  for (int i=0;i<9;++i){ ld[i] = __builtin_inff(); li[i] = 0x7fffffff; }
  int j0 = chunk*256;
  for (int j = j0; j < j0+256; ++j){
    float dx = cx[j]-qx, dy = cy[j]-qy, dz = cz[j]-qz;
    float d2 = dx*dx; d2 = d2 + dy*dy; d2 = d2 + dz*dz;
    if (d2 < ld[8]){          // strict <: equal d2 keeps lower index (top_k tie rule)
      ld[8] = d2; li[8] = j;
      #pragma unroll
      for (int i=8;i>0;--i){
        bool sw = ld[i] < ld[i-1];   // strict: stays below equals -> stable
        float ta = ld[i-1], tb = ld[i]; int ia = li[i-1], ib = li[i];
        ld[i-1] = sw ? tb : ta;  ld[i] = sw ? ta : tb;
        li[i-1] = sw ? ib : ia;  li[i] = sw ? ia : ib;
      }
    }
  }
  int base = (ql*16 + chunk)*9;
  #pragma unroll
  for (int i=0;i<9;++i){ md[base+i]=ld[i]; mi[base+i]=li[i]; }
  __syncthreads();
  if (t < 64){
    int q = t;
    int nq2 = qb*64 + q;
    float qx2 = cx[nq2], qy2 = cy[nq2];
    #pragma unroll
    for (int c=0;c<16;++c) pcs[q*16+c]=0;
    float* outp = geom + ((size_t)(b*4096 + nq2))*32;  // 8 * 4 floats
    for (int pick=0;pick<9;++pick){
      float bd = __builtin_inff(); int bi = 0x7fffffff; int bc = 0;
      #pragma unroll
      for (int c=0;c<16;++c){
        int pc = pcs[q*16+c];
        float dv = md[(q*16+c)*9 + pc];
        int iv = mi[(q*16+c)*9 + pc];
        bool better = (dv < bd) || (dv == bd && iv < bi);
        bd = better ? dv : bd; bi = better ? iv : bi; bc = better ? c : bc;
      }
      pcs[q*16+bc] += 1;
      if (pick > 0){   // drop first pick (self / min), keep 8
        float rx = cx[bi]-qx2, ry = cy[bi]-qy2;
        float rd = sqrtf(bd);
        v4f g; g[0]=rd; g[1]=rx; g[2]=ry; g[3]=fminf(rd,1.0f);
        *reinterpret_cast<v4f*>(outp + (pick-1)*4) = g;
      }
    }
  }
}

// ---------------------------------------------------------------------------
// K2: per-row h = relu(LN(geom@W1+b1)); z = h@G via MFMA; per-row m, inv;
//     h' = sum_k inv*h (bf16), S1 = sum inv, S2 = sum m*inv.
// grid: 512 blocks x 256 (256 rows/block = 32 points)
// ---------------------------------------------------------------------------
__global__ __launch_bounds__(256) void k_hbuild(
    const float* __restrict__ geom,
    const float* __restrict__ W1, const float* __restrict__ b1,
    const float* __restrict__ g1, const float* __restrict__ bt1,
    const unsigned short* __restrict__ Gm,
    const float* __restrict__ w2bar, const float* __restrict__ ubar,
    const float* __restrict__ scal,
    unsigned short* __restrict__ hprime, float* __restrict__ S1, float* __restrict__ S2)
{
  __shared__ v8s htile_v[256*8];          // 256 rows x 64 bf16, 16B-chunk XOR swizzle
  __shared__ __align__(16) float sW1[256];
  __shared__ __align__(16) float sb1[64], sg1[64], sbt1[64], swb[64], su[64];
  __shared__ float sinv[256], sminv[256];
  int t = threadIdx.x;
  sW1[t] = W1[t];
  if (t < 64){ sb1[t]=b1[t]; sg1[t]=g1[t]; sbt1[t]=bt1[t]; swb[t]=w2bar[t]; su[t]=ubar[t]; }
  int r0 = blockIdx.x * 256;
  v4f gv = reinterpret_cast<const v4f*>(geom)[r0 + t];
  __syncthreads();
  // ---- phase A: t1 = geom@W1+b1, LN(64), relu -> h (registers) ----
  float t1[64];
  #pragma unroll
  for (int l=0;l<64;l+=4){
    v4f w0 = *reinterpret_cast<const v4f*>(&sW1[l]);
    v4f w1 = *reinterpret_cast<const v4f*>(&sW1[64+l]);
    v4f w2 = *reinterpret_cast<const v4f*>(&sW1[128+l]);
    v4f w3 = *reinterpret_cast<const v4f*>(&sW1[192+l]);
    v4f bb = *reinterpret_cast<const v4f*>(&sb1[l]);
    #pragma unroll
    for (int e=0;e<4;++e)
      t1[l+e] = bb[e] + gv[0]*w0[e] + gv[1]*w1[e] + gv[2]*w2[e] + gv[3]*w3[e];
  }
  float s=0.f, s2=0.f;
  #pragma unroll
  for (int l=0;l<64;++l){ s += t1[l]; s2 += t1[l]*t1[l]; }
  float mu = s*(1.f/64.f);
  float var = s2*(1.f/64.f) - mu*mu;
  float inv = 1.0f/sqrtf(var+EPS);
  #pragma unroll
  for (int l=0;l<64;++l){
    float hv = (t1[l]-mu)*inv*sg1[l] + sbt1[l];
    t1[l] = hv > 0.f ? hv : 0.f;
  }
  #pragma unroll
  for (int cc=0;cc<8;++cc){
    v8s pk;
    #pragma unroll
    for (int e=0;e<8;++e) pk[e] = (short)f2bf(t1[cc*8+e]);
    htile_v[t*8 + (cc ^ (t&7))] = pk;
  }
  __syncthreads();
  // ---- phase B/C: z = h@G (MFMA), row stats ----
  int lane = t & 63, w = t >> 6;
  int l15 = lane & 15, l4 = lane >> 4;
  v8s gf[8];
  const v8s* Gv = reinterpret_cast<const v8s*>(Gm);   // G symmetric: row n gives B[k][n]
  #pragma unroll
  for (int tc=0;tc<4;++tc)
    #pragma unroll
    for (int kk=0;kk<2;++kk)
      gf[tc*2+kk] = Gv[(tc*16+l15)*8 + kk*4 + l4];
  float b2bar = scal[0], c0v = scal[1];
  const unsigned short* hs = reinterpret_cast<const unsigned short*>(htile_v);
  for (int rt = w; rt < 16; rt += 4){
    int arow = rt*16 + l15;
    v8s af0 = htile_v[arow*8 + ((l4)   ^ (arow&7))];
    v8s af1 = htile_v[arow*8 + ((4+l4) ^ (arow&7))];
    v4f acc[4];
    #pragma unroll
    for (int tc=0;tc<4;++tc){
      acc[tc] = (v4f){0.f,0.f,0.f,0.f};
      acc[tc] = __builtin_amdgcn_mfma_f32_16x16x32_bf16(af0, gf[tc*2+0], acc[tc], 0,0,0);
      acc[tc] = __builtin_amdgcn_mfma_f32_16x16x32_bf16(af1, gf[tc*2+1], acc[tc], 0,0,0);
    }
    float zh[4]={0,0,0,0}, hwb[4]={0,0,0,0}, hu[4]={0,0,0,0};
    #pragma unroll
    for (int r=0;r<4;++r){
      int row = rt*16 + l4*4 + r;
      #pragma unroll
      for (int tc=0;tc<4;++tc){
        int col = tc*16 + l15;
        int chunk = col >> 3;
        unsigned short us = hs[row*64 + ((chunk ^ (row&7))<<3) + (col&7)];
        float hval = bf2f(us);
        zh[r] += acc[tc][r]*hval;
        hwb[r] += hval*swb[col];
        hu[r]  += hval*su[col];
      }
    }
    #pragma unroll
    for (int mk=1; mk<16; mk<<=1){
      #pragma unroll
      for (int r=0;r<4;++r){
        zh[r] += __shfl_xor(zh[r], mk, 64);
        hwb[r]+= __shfl_xor(hwb[r],mk, 64);
        hu[r] += __shfl_xor(hu[r], mk, 64);
      }
    }
    if (l15 == 0){
      #pragma unroll
      for (int r=0;r<4;++r){
        int row = rt*16 + l4*4 + r;
        float mm = hwb[r] + b2bar;
        float vv = zh[r] + 2.f*hu[r] + c0v - mm*mm;
        float iv = 1.0f/sqrtf(vv + EPS);
        sinv[row]  = iv;
        sminv[row] = mm*iv;
      }
    }
  }
  __syncthreads();
  // ---- phase D: h' = sum_k inv*h ; S1,S2 ----
  int p = t >> 3, jg = t & 7;
  float hp[8] = {0,0,0,0,0,0,0,0};
  #pragma unroll
  for (int k=0;k<8;++k){
    int row = p*8 + k;
    float iv = sinv[row];
    v8s hv8 = htile_v[row*8 + (jg ^ (row&7))];
    #pragma unroll
    for (int e=0;e<8;++e) hp[e] += iv * bf2f((unsigned short)hv8[e]);
  }
  v8s pk;
  #pragma unroll
  for (int e=0;e<8;++e) pk[e] = (short)f2bf(hp[e]);
  int gp = blockIdx.x*32 + p;
  reinterpret_cast<v8s*>(hprime)[gp*8 + jg] = pk;
  if (jg == 0){
    float a=0.f, bb=0.f;
    #pragma unroll
    for (int k=0;k<8;++k){ a += sinv[p*8+k]; bb += sminv[p*8+k]; }
    S1[gp]=a; S2[gp]=bb;
  }
}

// ---------------------------------------------------------------------------
// K4: segment sums + counts via LDS [64 seg][256 cols] accumulators
// grid: B * 3 colchunks * 4 nsplits = 48 blocks x 256
// ---------------------------------------------------------------------------
__global__ __launch_bounds__(256) void k_segsum(const float* __restrict__ features,
                                                const int* __restrict__ labels,
                                                float* __restrict__ sums,
                                                float* __restrict__ cnt)
{
  __shared__ float part[64*256];
  __shared__ int lcnt[64];
  int t = threadIdx.x;
  int blk = blockIdx.x;
  int b = blk / 12; int rem = blk - b*12;
  int cc = rem >> 2; int ns = rem & 3;
  for (int i=t;i<64*256;i+=256) part[i]=0.f;
  if (t < 64) lcnt[t]=0;
  __syncthreads();
  int c0 = cc*256;
  int n0 = ns*1024;
  const float* fb = features + (size_t)b*4096*768;
  const int* lb = labels + b*4096;
  for (int n=n0;n<n0+1024;++n){
    int s = lb[n];
    part[s*256+t] += fb[(size_t)n*768 + c0 + t];
  }
  if (cc == 0){
    for (int n=n0+t;n<n0+1024;n+=256) atomicAdd(&lcnt[lb[n]],1);
  }
  __syncthreads();
  float* sb = sums + (size_t)b*64*768;
  for (int i=t;i<64*256;i+=256){
    int s = i>>8, c = i&255;
    atomicAdd(&sb[s*768 + c0 + c], part[i]);
  }
  if (cc==0 && t<64) atomicAdd(&cnt[b*64+t], (float)lcnt[t]);
}

// ---------------------------------------------------------------------------
// K5: segment MLP: agg = LN(relu(LN(means@A1+ab1))@A2+ab2). grid: 256 blocks
// ---------------------------------------------------------------------------
__global__ __launch_bounds__(256) void k_segmlp(const float* __restrict__ sums,
    const float* __restrict__ cnt,
    const float* __restrict__ A1, const float* __restrict__ ab1,
    const float* __restrict__ ag1, const float* __restrict__ abt1,
    const float* __restrict__ A2, const float* __restrict__ ab2,
    const float* __restrict__ ag2, const float* __restrict__ abt2,
    float* __restrict__ agg)
{
  __shared__ float meanr[768];
  __shared__ float ah[128];
  __shared__ float red[256];
  __shared__ float sstat[2];
  int t = threadIdx.x;
  int bs = blockIdx.x;
  float cv = cnt[bs];
  float ic = 1.0f / fmaxf(cv, 1.0f);
  for (int i=t;i<768;i+=256) meanr[i] = sums[(size_t)bs*768+i]*ic;
  __syncthreads();
  float t1 = 0.f;
  if (t < 128){
    t1 = ab1[t];
    #pragma unroll 4
    for (int j=0;j<768;++j) t1 += meanr[j]*A1[j*128+t];
  }
  red[t] = (t<128) ? t1 : 0.f;
  __syncthreads();
  if (t == 0){
    float s=0.f, sq=0.f;
    for (int i=0;i<128;++i){ float v=red[i]; s+=v; sq+=v*v; }
    float mm = s*(1.f/128.f);
    sstat[0]=mm; sstat[1]=sq*(1.f/128.f)-mm*mm;
  }
  __syncthreads();
  if (t < 128){
    float iv = 1.0f/sqrtf(sstat[1]+EPS);
    float a = (t1-sstat[0])*iv*ag1[t] + abt1[t];
    ah[t] = fmaxf(a, 0.f);
  }
  __syncthreads();
  float o0 = ab2[t], o1 = ab2[t+256], o2 = ab2[t+512];
  #pragma unroll 4
  for (int j=0;j<128;++j){
    float hv = ah[j];
    o0 += hv*A2[j*768+t];
    o1 += hv*A2[j*768+t+256];
    o2 += hv*A2[j*768+t+512];
  }
  red[t] = o0+o1+o2;
  __syncthreads();
  if (t==0){ float s=0.f; for (int i=0;i<256;++i) s+=red[i]; sstat[0]=s*(1.f/768.f); }
  __syncthreads();
  red[t] = o0*o0+o1*o1+o2*o2;
  __syncthreads();
  if (t==0){ float s=0.f; for (int i=0;i<256;++i) s+=red[i]; sstat[1]=s*(1.f/768.f)-sstat[0]*sstat[0]; }
  __syncthreads();
  float iv = 1.0f/sqrtf(sstat[1]+EPS);
  float mm = sstat[0];
  agg[(size_t)bs*768 + t]       = (o0-mm)*iv*ag2[t]     + abt2[t];
  agg[(size_t)bs*768 + t + 256] = (o1-mm)*iv*ag2[t+256] + abt2[t+256];
  agg[(size_t)bs*768 + t + 512] = (o2-mm)*iv*ag2[t+512] + abt2[t+512];
}

// ---------------------------------------------------------------------------
// K3: ctx GEMM (h'@W2) + full epilogue -> out (fused final combine)
// grid: 256 blocks x 256 (64 rows/block, wave per 16-row tile, 48 col tiles)
// ---------------------------------------------------------------------------
__global__ __launch_bounds__(256) void k_final(
  const unsigned short* __restrict__ hprime, const unsigned short* __restrict__ W2T,
  const float* __restrict__ S1, const float* __restrict__ S2,
  const float* __restrict__ g2, const float* __restrict__ b2, const float* __restrict__ bt2,
  const float* __restrict__ features, const int* __restrict__ labels,
  const float* __restrict__ cnt, const float* __restrict__ agg,
  float* __restrict__ out)
{
  int t=threadIdx.x; int lane=t&63; int w=t>>6; int l15=lane&15, l4=lane>>4;
  int rowt = blockIdx.x*64 + w*16;
  const v8s* hv = reinterpret_cast<const v8s*>(hprime);
  v8s af0 = hv[(rowt+l15)*8 + l4];
  v8s af1 = hv[(rowt+l15)*8 + 4 + l4];
  float s1r[4], s2r[4], cntr[4]; int labr[4], br[4];
  #pragma unroll
  for (int r=0;r<4;++r){
    int row = rowt + l4*4 + r;
    s1r[r]=S1[row]; s2r[r]=S2[row];
    labr[r]=labels[row]; br[r]=row>>12;
    cntr[r]=cnt[br[r]*64 + labr[r]];
  }
  const v8s* wtv = reinterpret_cast<const v8s*>(W2T);
  for (int tc=0;tc<48;++tc){
    v8s bf0 = wtv[(tc*16+l15)*8 + l4];
    v8s bf1 = wtv[(tc*16+l15)*8 + 4 + l4];
    v4f acc = (v4f){0.f,0.f,0.f,0.f};
    acc = __builtin_amdgcn_mfma_f32_16x16x32_bf16(af0, bf0, acc, 0,0,0);
    acc = __builtin_amdgcn_mfma_f32_16x16x32_bf16(af1, bf1, acc, 0,0,0);
    int c = tc*16 + l15;
    float g2c=g2[c], b2c=b2[c], bt2c=bt2[c];
    #pragma unroll
    for (int r=0;r<4;++r){
      int row = rowt + l4*4 + r;
      float ctxv = 0.1f*(g2c*((acc[r] + b2c*s1r[r] - s2r[r])*0.125f) + bt2c);
      size_t o = (size_t)row*768 + c;
      float f = features[o];
      float av = agg[((size_t)(br[r]*64 + labr[r]))*768 + c];
      float enh = (cntr[r] >= 2.0f) ? (0.9f*f + 0.1f*av) : f;
      out[o] = enh + ctxv;
    }
  }
}

// ---------------------------------------------------------------------------
extern "C" void kernel_launch(void* const* d_in, const int* in_sizes, int n_in,
                              void* d_out, int out_size, void* d_ws, size_t ws_size,
                              hipStream_t stream) {
  const float* coords   = (const float*)d_in[0];
  const float* features = (const float*)d_in[1];
  const int*   labels   = (const int*)  d_in[2];
  const float* W1  = (const float*)d_in[3];
  const float* b1  = (const float*)d_in[4];
  const float* g1  = (const float*)d_in[5];
  const float* bt1 = (const float*)d_in[6];
  const float* W2  = (const float*)d_in[7];
  const float* b2  = (const float*)d_in[8];
  const float* g2  = (const float*)d_in[9];
  const float* bt2 = (const float*)d_in[10];
  const float* A1  = (const float*)d_in[11];
  const float* ab1 = (const float*)d_in[12];
  const float* ag1 = (const float*)d_in[13];
  const float* abt1= (const float*)d_in[14];
  const float* A2  = (const float*)d_in[15];
  const float* ab2 = (const float*)d_in[16];
  const float* ag2 = (const float*)d_in[17];
  const float* abt2= (const float*)d_in[18];

  char* ws = (char*)d_ws;
  size_t off = 0;
  auto alloc = [&](size_t bytes){ size_t o = off; off = (off + bytes + 255) & ~(size_t)255; return o; };
  float*          geom   = (float*)(ws + alloc((size_t)131072*4*4));
  unsigned short* hprime = (unsigned short*)(ws + alloc((size_t)16384*64*2));
  float*          S1w    = (float*)(ws + alloc(16384*4));
  float*          S2w    = (float*)(ws + alloc(16384*4));
  unsigned short* W2T    = (unsigned short*)(ws + alloc(768*64*2));
  unsigned short* Gm     = (unsigned short*)(ws + alloc(64*64*2));
  float*          w2bar  = (float*)(ws + alloc(64*4));
  float*          ubar   = (float*)(ws + alloc(64*4));
  float*          scal   = (float*)(ws + alloc(2*4));
  float*          sums   = (float*)(ws + alloc((size_t)4*64*768*4));
  float*          cntw   = (float*)(ws + alloc(4*64*4));
  float*          agg    = (float*)(ws + alloc((size_t)4*64*768*4));

  // sums (786432B) and cnt (1024B) are contiguous (786432 % 256 == 0)
  hipMemsetAsync(sums, 0, (size_t)(4*64*768 + 4*64)*4, stream);

  k_prep  <<<dim3(113), dim3(256), 0, stream>>>(W2, b2, Gm, w2bar, ubar, scal, W2T);
  k_knn   <<<dim3(256), dim3(1024),0, stream>>>(coords, geom);
  k_hbuild<<<dim3(512), dim3(256), 0, stream>>>(geom, W1, b1, g1, bt1, Gm, w2bar, ubar, scal,
                                                hprime, S1w, S2w);
  k_segsum<<<dim3(48),  dim3(256), 0, stream>>>(features, labels, sums, cntw);
  k_segmlp<<<dim3(256), dim3(256), 0, stream>>>(sums, cntw, A1, ab1, ag1, abt1,
                                                A2, ab2, ag2, abt2, agg);
  k_final <<<dim3(256), dim3(256), 0, stream>>>(hprime, W2T, S1w, S2w, g2, b2, bt2,
                                                features, labels, cntw, agg, (float*)d_out);
}

// Round 2
// 453.946 us; speedup vs baseline: 1.1141x; 1.1141x over previous
//
#include <hip/hip_runtime.h>
#include <math.h>

typedef short v8s __attribute__((ext_vector_type(8)));
typedef float v4f __attribute__((ext_vector_type(4)));

#define EPS 1e-5f

__device__ __forceinline__ unsigned short f2bf(float x){
  unsigned u = __float_as_uint(x);
  return (unsigned short)((u + 0x7fffu + ((u>>16)&1u)) >> 16);
}
__device__ __forceinline__ float bf2f(unsigned short us){
  return __uint_as_float(((unsigned)us)<<16);
}

// ---------------------------------------------------------------------------
// K0: prep — G = W2 W2^T/768 (bf16), w2bar, u = W2 b2/768, b2bar, c0, W2T(bf16)
// ---------------------------------------------------------------------------
__global__ __launch_bounds__(256) void k_prep(const float* __restrict__ W2,
                                              const float* __restrict__ b2,
                                              unsigned short* __restrict__ Gm,
                                              float* __restrict__ w2bar,
                                              float* __restrict__ ubar,
                                              float* __restrict__ scal,
                                              unsigned short* __restrict__ W2T)
{
  __shared__ float row[768];
  __shared__ float part[256];
  int t = threadIdx.x;
  int blk = blockIdx.x;
  if (blk < 64){
    for (int c = t; c < 768; c += 256) row[c] = W2[blk*768 + c];
    __syncthreads();
    int jp = t & 63, quarter = t >> 6;
    float acc = 0.f;
    int c0 = quarter*192;
    for (int c = c0; c < c0+192; ++c) acc += row[c]*W2[jp*768 + c];
    part[t] = acc;
    __syncthreads();
    if (t < 64){
      float sv = part[t] + part[t+64] + part[t+128] + part[t+192];
      Gm[blk*64 + t] = f2bf(sv * (1.f/768.f));
    }
  } else if (blk == 64){
    if (t < 64){
      float sw=0.f, sus=0.f;
      for (int c=0;c<768;++c){ float wv=W2[t*768+c]; sw+=wv; sus+=wv*b2[c]; }
      w2bar[t]=sw*(1.f/768.f); ubar[t]=sus*(1.f/768.f);
    } else if (t == 64){
      float sb=0.f, sb2=0.f;
      for (int c=0;c<768;++c){ float v=b2[c]; sb+=v; sb2+=v*v; }
      scal[0]=sb*(1.f/768.f); scal[1]=sb2*(1.f/768.f);
    }
  } else {
    int bi = blk - 65;
    int c0 = bi*16;
    for (int idx = t; idx < 1024; idx += 256){
      int c = c0 + (idx >> 6), j = idx & 63;
      W2T[c*64 + j] = f2bf(W2[j*768 + c]);
    }
  }
}

// ---------------------------------------------------------------------------
// K1: exact KNN (top-9 by (d2, idx) lex, matching jax.lax.top_k ties) + geom
// grid: B*64 = 256 blocks x 1024 threads. thread = (query in 64, chunk in 16)
// ---------------------------------------------------------------------------
__global__ __launch_bounds__(1024) void k_knn(const float* __restrict__ coords,
                                              float* __restrict__ geom)
{
#pragma clang fp contract(off)
  __shared__ float cx[4096], cy[4096], cz[4096];
  __shared__ float md[64*16*9];
  __shared__ int   mi[64*16*9];
  __shared__ int   pcs[64*16];
  int t = threadIdx.x;
  int b  = blockIdx.x >> 6;
  int qb = blockIdx.x & 63;
  const float* cb = coords + (size_t)b*4096*3;
  for (int n = t; n < 4096; n += 1024){
    cx[n] = cb[n*3+0]; cy[n] = cb[n*3+1]; cz[n] = cb[n*3+2];
  }
  __syncthreads();
  int ql = t & 63, chunk = t >> 6;
  int nq = qb*64 + ql;
  float qx = cx[nq], qy = cy[nq], qz = cz[nq];
  float ld[9]; int li[9];
  #pragma unroll
  for (int i=0;i<9;++i){ ld[i] = __builtin_inff(); li[i] = 0x7fffffff; }
  int j0 = chunk*256;
  for (int j = j0; j < j0+256; ++j){
    float dx = cx[j]-qx, dy = cy[j]-qy, dz = cz[j]-qz;
    float d2 = dx*dx; d2 = d2 + dy*dy; d2 = d2 + dz*dz;
    if (d2 < ld[8]){          // strict <: equal d2 keeps lower index (top_k tie rule)
      ld[8] = d2; li[8] = j;
      #pragma unroll
      for (int i=8;i>0;--i){
        bool sw = ld[i] < ld[i-1];   // strict: stays below equals -> stable
        float ta = ld[i-1], tb = ld[i]; int ia = li[i-1], ib = li[i];
        ld[i-1] = sw ? tb : ta;  ld[i] = sw ? ta : tb;
        li[i-1] = sw ? ib : ia;  li[i] = sw ? ia : ib;
      }
    }
  }
  int base = (ql*16 + chunk)*9;
  #pragma unroll
  for (int i=0;i<9;++i){ md[base+i]=ld[i]; mi[base+i]=li[i]; }
  __syncthreads();
  if (t < 64){
    int q = t;
    int nq2 = qb*64 + q;
    float qx2 = cx[nq2], qy2 = cy[nq2];
    #pragma unroll
    for (int c=0;c<16;++c) pcs[q*16+c]=0;
    float* outp = geom + ((size_t)(b*4096 + nq2))*32;  // 8 * 4 floats
    for (int pick=0;pick<9;++pick){
      float bd = __builtin_inff(); int bi = 0x7fffffff; int bc = 0;
      #pragma unroll
      for (int c=0;c<16;++c){
        int pc = pcs[q*16+c];
        float dv = md[(q*16+c)*9 + pc];
        int iv = mi[(q*16+c)*9 + pc];
        bool better = (dv < bd) || (dv == bd && iv < bi);
        bd = better ? dv : bd; bi = better ? iv : bi; bc = better ? c : bc;
      }
      pcs[q*16+bc] += 1;
      if (pick > 0){   // drop first pick (self / min), keep 8
        float rx = cx[bi]-qx2, ry = cy[bi]-qy2;
        float rd = sqrtf(bd);
        v4f g; g[0]=rd; g[1]=rx; g[2]=ry; g[3]=fminf(rd,1.0f);
        *reinterpret_cast<v4f*>(outp + (pick-1)*4) = g;
      }
    }
  }
}

// ---------------------------------------------------------------------------
// K2: per-row h = relu(LN(geom@W1+b1)); z = h@G via MFMA; per-row m, inv;
//     h' = sum_k inv*h (bf16), S1 = sum inv, S2 = sum m*inv.
// grid: 512 blocks x 256 (256 rows/block = 32 points)
// ---------------------------------------------------------------------------
__global__ __launch_bounds__(256) void k_hbuild(
    const float* __restrict__ geom,
    const float* __restrict__ W1, const float* __restrict__ b1,
    const float* __restrict__ g1, const float* __restrict__ bt1,
    const unsigned short* __restrict__ Gm,
    const float* __restrict__ w2bar, const float* __restrict__ ubar,
    const float* __restrict__ scal,
    unsigned short* __restrict__ hprime, float* __restrict__ S1, float* __restrict__ S2)
{
  __shared__ v8s htile_v[256*8];          // 256 rows x 64 bf16, 16B-chunk XOR swizzle
  __shared__ __align__(16) float sW1[256];
  __shared__ __align__(16) float sb1[64], sg1[64], sbt1[64], swb[64], su[64];
  __shared__ float sinv[256], sminv[256];
  int t = threadIdx.x;
  sW1[t] = W1[t];
  if (t < 64){ sb1[t]=b1[t]; sg1[t]=g1[t]; sbt1[t]=bt1[t]; swb[t]=w2bar[t]; su[t]=ubar[t]; }
  int r0 = blockIdx.x * 256;
  v4f gv = reinterpret_cast<const v4f*>(geom)[r0 + t];
  __syncthreads();
  // ---- phase A: t1 = geom@W1+b1, LN(64), relu -> h (registers) ----
  float t1[64];
  #pragma unroll
  for (int l=0;l<64;l+=4){
    v4f w0 = *reinterpret_cast<const v4f*>(&sW1[l]);
    v4f w1 = *reinterpret_cast<const v4f*>(&sW1[64+l]);
    v4f w2 = *reinterpret_cast<const v4f*>(&sW1[128+l]);
    v4f w3 = *reinterpret_cast<const v4f*>(&sW1[192+l]);
    v4f bb = *reinterpret_cast<const v4f*>(&sb1[l]);
    #pragma unroll
    for (int e=0;e<4;++e)
      t1[l+e] = bb[e] + gv[0]*w0[e] + gv[1]*w1[e] + gv[2]*w2[e] + gv[3]*w3[e];
  }
  float s=0.f, s2=0.f;
  #pragma unroll
  for (int l=0;l<64;++l){ s += t1[l]; s2 += t1[l]*t1[l]; }
  float mu = s*(1.f/64.f);
  float var = s2*(1.f/64.f) - mu*mu;
  float inv = 1.0f/sqrtf(var+EPS);
  #pragma unroll
  for (int l=0;l<64;++l){
    float hv = (t1[l]-mu)*inv*sg1[l] + sbt1[l];
    t1[l] = hv > 0.f ? hv : 0.f;
  }
  #pragma unroll
  for (int cc=0;cc<8;++cc){
    v8s pk;
    #pragma unroll
    for (int e=0;e<8;++e) pk[e] = (short)f2bf(t1[cc*8+e]);
    htile_v[t*8 + (cc ^ (t&7))] = pk;
  }
  __syncthreads();
  // ---- phase B/C: z = h@G (MFMA), row stats ----
  int lane = t & 63, w = t >> 6;
  int l15 = lane & 15, l4 = lane >> 4;
  v8s gf[8];
  const v8s* Gv = reinterpret_cast<const v8s*>(Gm);   // G symmetric: row n gives B[k][n]
  #pragma unroll
  for (int tc=0;tc<4;++tc)
    #pragma unroll
    for (int kk=0;kk<2;++kk)
      gf[tc*2+kk] = Gv[(tc*16+l15)*8 + kk*4 + l4];
  float b2bar = scal[0], c0v = scal[1];
  const unsigned short* hs = reinterpret_cast<const unsigned short*>(htile_v);
  for (int rt = w; rt < 16; rt += 4){
    int arow = rt*16 + l15;
    v8s af0 = htile_v[arow*8 + ((l4)   ^ (arow&7))];
    v8s af1 = htile_v[arow*8 + ((4+l4) ^ (arow&7))];
    v4f acc[4];
    #pragma unroll
    for (int tc=0;tc<4;++tc){
      acc[tc] = (v4f){0.f,0.f,0.f,0.f};
      acc[tc] = __builtin_amdgcn_mfma_f32_16x16x32_bf16(af0, gf[tc*2+0], acc[tc], 0,0,0);
      acc[tc] = __builtin_amdgcn_mfma_f32_16x16x32_bf16(af1, gf[tc*2+1], acc[tc], 0,0,0);
    }
    float zh[4]={0,0,0,0}, hwb[4]={0,0,0,0}, hu[4]={0,0,0,0};
    #pragma unroll
    for (int r=0;r<4;++r){
      int row = rt*16 + l4*4 + r;
      #pragma unroll
      for (int tc=0;tc<4;++tc){
        int col = tc*16 + l15;
        int chunk = col >> 3;
        unsigned short us = hs[row*64 + ((chunk ^ (row&7))<<3) + (col&7)];
        float hval = bf2f(us);
        zh[r] += acc[tc][r]*hval;
        hwb[r] += hval*swb[col];
        hu[r]  += hval*su[col];
      }
    }
    #pragma unroll
    for (int mk=1; mk<16; mk<<=1){
      #pragma unroll
      for (int r=0;r<4;++r){
        zh[r] += __shfl_xor(zh[r], mk, 64);
        hwb[r]+= __shfl_xor(hwb[r],mk, 64);
        hu[r] += __shfl_xor(hu[r], mk, 64);
      }
    }
    if (l15 == 0){
      #pragma unroll
      for (int r=0;r<4;++r){
        int row = rt*16 + l4*4 + r;
        float mm = hwb[r] + b2bar;
        float vv = zh[r] + 2.f*hu[r] + c0v - mm*mm;
        float iv = 1.0f/sqrtf(vv + EPS);
        sinv[row]  = iv;
        sminv[row] = mm*iv;
      }
    }
  }
  __syncthreads();
  // ---- phase D: h' = sum_k inv*h ; S1,S2 ----
  int p = t >> 3, jg = t & 7;
  float hp[8] = {0,0,0,0,0,0,0,0};
  #pragma unroll
  for (int k=0;k<8;++k){
    int row = p*8 + k;
    float iv = sinv[row];
    v8s hv8 = htile_v[row*8 + (jg ^ (row&7))];
    #pragma unroll
    for (int e=0;e<8;++e) hp[e] += iv * bf2f((unsigned short)hv8[e]);
  }
  v8s pk;
  #pragma unroll
  for (int e=0;e<8;++e) pk[e] = (short)f2bf(hp[e]);
  int gp = blockIdx.x*32 + p;
  reinterpret_cast<v8s*>(hprime)[gp*8 + jg] = pk;
  if (jg == 0){
    float a=0.f, bb=0.f;
    #pragma unroll
    for (int k=0;k<8;++k){ a += sinv[p*8+k]; bb += sminv[p*8+k]; }
    S1[gp]=a; S2[gp]=bb;
  }
}

// ---------------------------------------------------------------------------
// K4: segment partial sums via LDS accumulators + float4 loads.
// grid: B(4) x NS(16 row-chunks of 256) x CC(3 col-chunks of 256) = 192 blocks
// Writes partials[b][ns][64][768-slice] (reduced later in k_segmlp) — no
// global atomics, no memset.
// ---------------------------------------------------------------------------
__global__ __launch_bounds__(256) void k_segsum(const float* __restrict__ features,
                                                const int* __restrict__ labels,
                                                float* __restrict__ partials,
                                                float* __restrict__ cntp)
{
  __shared__ float part[4][64][64];   // [e][seg][col-quad]; bank = cq&31 -> 2-way
  __shared__ int lab[256];
  __shared__ int lcnt[64];
  int t = threadIdx.x;
  int blk = blockIdx.x;
  int b = blk / 48;
  int rem = blk - b*48;
  int ns = rem / 3, cc = rem - ns*3;
  int n0 = ns*256, c0 = cc*256;
  float* pf = &part[0][0][0];
  for (int i=t;i<16384;i+=256) pf[i]=0.f;
  if (t<64) lcnt[t]=0;
  lab[t] = labels[b*4096 + n0 + t];
  __syncthreads();
  int rq = t>>6, cq = t&63;           // 4 row-slots x 64 col-quads (float4)
  const float* fb = features + (size_t)b*4096*768 + (size_t)n0*768 + c0 + cq*4;
  for (int itg=0; itg<64; itg+=4){
    v4f v[4]; int ss[4];
    #pragma unroll
    for (int u=0;u<4;++u){
      int row = (itg+u)*4 + rq;
      ss[u] = lab[row];
      v[u] = *reinterpret_cast<const v4f*>(fb + (size_t)row*768);
    }
    #pragma unroll
    for (int u=0;u<4;++u){
      #pragma unroll
      for (int e=0;e<4;++e)
        atomicAdd(&part[e][ss[u]][cq], v[u][e]);
    }
  }
  if (cc==0) atomicAdd(&lcnt[lab[t]], 1);
  __syncthreads();
  float* pb = partials + ((size_t)(b*16+ns)*64)*768 + c0;
  for (int i=t;i<16384;i+=256){
    int s = i>>8, c = i&255;
    pb[(size_t)s*768 + c] = part[c&3][s][c>>2];
  }
  if (cc==0 && t<64) cntp[(b*16+ns)*64 + t] = (float)lcnt[t];
}

// ---------------------------------------------------------------------------
// K5: reduce partials -> means; segment MLP; writes agg + total counts cntw
// grid: 256 blocks (one per (b,seg)) x 256
// ---------------------------------------------------------------------------
__global__ __launch_bounds__(256) void k_segmlp(const float* __restrict__ partials,
    const float* __restrict__ cntp,
    const float* __restrict__ A1, const float* __restrict__ ab1,
    const float* __restrict__ ag1, const float* __restrict__ abt1,
    const float* __restrict__ A2, const float* __restrict__ ab2,
    const float* __restrict__ ag2, const float* __restrict__ abt2,
    float* __restrict__ agg, float* __restrict__ cntw)
{
  __shared__ float meanr[768];
  __shared__ float ah[128];
  __shared__ float red[256];
  __shared__ float sstat[2];
  __shared__ float scnt;
  int t = threadIdx.x;
  int bs = blockIdx.x;
  int b = bs >> 6, sseg = bs & 63;
  if (t == 0){
    float c = 0.f;
    for (int ns=0;ns<16;++ns) c += cntp[(b*16+ns)*64 + sseg];
    scnt = c; cntw[bs] = c;
  }
  __syncthreads();
  float cv = scnt;
  float ic = 1.0f / fmaxf(cv, 1.0f);
  for (int i=t;i<768;i+=256){
    float acc = 0.f;
    #pragma unroll 4
    for (int ns=0;ns<16;++ns)
      acc += partials[((size_t)(b*16+ns)*64 + sseg)*768 + i];
    meanr[i] = acc*ic;
  }
  __syncthreads();
  float t1 = 0.f;
  if (t < 128){
    t1 = ab1[t];
    #pragma unroll 4
    for (int j=0;j<768;++j) t1 += meanr[j]*A1[j*128+t];
  }
  red[t] = (t<128) ? t1 : 0.f;
  __syncthreads();
  if (t == 0){
    float s=0.f, sq=0.f;
    for (int i=0;i<128;++i){ float v=red[i]; s+=v; sq+=v*v; }
    float mm = s*(1.f/128.f);
    sstat[0]=mm; sstat[1]=sq*(1.f/128.f)-mm*mm;
  }
  __syncthreads();
  if (t < 128){
    float iv = 1.0f/sqrtf(sstat[1]+EPS);
    float a = (t1-sstat[0])*iv*ag1[t] + abt1[t];
    ah[t] = fmaxf(a, 0.f);
  }
  __syncthreads();
  float o0 = ab2[t], o1 = ab2[t+256], o2 = ab2[t+512];
  #pragma unroll 4
  for (int j=0;j<128;++j){
    float hv = ah[j];
    o0 += hv*A2[j*768+t];
    o1 += hv*A2[j*768+t+256];
    o2 += hv*A2[j*768+t+512];
  }
  red[t] = o0+o1+o2;
  __syncthreads();
  if (t==0){ float s=0.f; for (int i=0;i<256;++i) s+=red[i]; sstat[0]=s*(1.f/768.f); }
  __syncthreads();
  red[t] = o0*o0+o1*o1+o2*o2;
  __syncthreads();
  if (t==0){ float s=0.f; for (int i=0;i<256;++i) s+=red[i]; sstat[1]=s*(1.f/768.f)-sstat[0]*sstat[0]; }
  __syncthreads();
  float iv = 1.0f/sqrtf(sstat[1]+EPS);
  float mm = sstat[0];
  agg[(size_t)bs*768 + t]       = (o0-mm)*iv*ag2[t]     + abt2[t];
  agg[(size_t)bs*768 + t + 256] = (o1-mm)*iv*ag2[t+256] + abt2[t+256];
  agg[(size_t)bs*768 + t + 512] = (o2-mm)*iv*ag2[t+512] + abt2[t+512];
}

// ---------------------------------------------------------------------------
// K3: ctx GEMM (h'@W2) + full epilogue -> out (fused final combine)
// grid: 256 blocks x 256 (64 rows/block, wave per 16-row tile, 48 col tiles)
// ---------------------------------------------------------------------------
__global__ __launch_bounds__(256) void k_final(
  const unsigned short* __restrict__ hprime, const unsigned short* __restrict__ W2T,
  const float* __restrict__ S1, const float* __restrict__ S2,
  const float* __restrict__ g2, const float* __restrict__ b2, const float* __restrict__ bt2,
  const float* __restrict__ features, const int* __restrict__ labels,
  const float* __restrict__ cnt, const float* __restrict__ agg,
  float* __restrict__ out)
{
  int t=threadIdx.x; int lane=t&63; int w=t>>6; int l15=lane&15, l4=lane>>4;
  int rowt = blockIdx.x*64 + w*16;
  const v8s* hv = reinterpret_cast<const v8s*>(hprime);
  v8s af0 = hv[(rowt+l15)*8 + l4];
  v8s af1 = hv[(rowt+l15)*8 + 4 + l4];
  float s1r[4], s2r[4], cntr[4]; int labr[4], br[4];
  #pragma unroll
  for (int r=0;r<4;++r){
    int row = rowt + l4*4 + r;
    s1r[r]=S1[row]; s2r[r]=S2[row];
    labr[r]=labels[row]; br[r]=row>>12;
    cntr[r]=cnt[br[r]*64 + labr[r]];
  }
  const v8s* wtv = reinterpret_cast<const v8s*>(W2T);
  for (int tc=0;tc<48;++tc){
    v8s bf0 = wtv[(tc*16+l15)*8 + l4];
    v8s bf1 = wtv[(tc*16+l15)*8 + 4 + l4];
    v4f acc = (v4f){0.f,0.f,0.f,0.f};
    acc = __builtin_amdgcn_mfma_f32_16x16x32_bf16(af0, bf0, acc, 0,0,0);
    acc = __builtin_amdgcn_mfma_f32_16x16x32_bf16(af1, bf1, acc, 0,0,0);
    int c = tc*16 + l15;
    float g2c=g2[c], b2c=b2[c], bt2c=bt2[c];
    #pragma unroll
    for (int r=0;r<4;++r){
      int row = rowt + l4*4 + r;
      float ctxv = 0.1f*(g2c*((acc[r] + b2c*s1r[r] - s2r[r])*0.125f) + bt2c);
      size_t o = (size_t)row*768 + c;
      float f = features[o];
      float av = agg[((size_t)(br[r]*64 + labr[r]))*768 + c];
      float enh = (cntr[r] >= 2.0f) ? (0.9f*f + 0.1f*av) : f;
      out[o] = enh + ctxv;
    }
  }
}

// ---------------------------------------------------------------------------
extern "C" void kernel_launch(void* const* d_in, const int* in_sizes, int n_in,
                              void* d_out, int out_size, void* d_ws, size_t ws_size,
                              hipStream_t stream) {
  const float* coords   = (const float*)d_in[0];
  const float* features = (const float*)d_in[1];
  const int*   labels   = (const int*)  d_in[2];
  const float* W1  = (const float*)d_in[3];
  const float* b1  = (const float*)d_in[4];
  const float* g1  = (const float*)d_in[5];
  const float* bt1 = (const float*)d_in[6];
  const float* W2  = (const float*)d_in[7];
  const float* b2  = (const float*)d_in[8];
  const float* g2  = (const float*)d_in[9];
  const float* bt2 = (const float*)d_in[10];
  const float* A1  = (const float*)d_in[11];
  const float* ab1 = (const float*)d_in[12];
  const float* ag1 = (const float*)d_in[13];
  const float* abt1= (const float*)d_in[14];
  const float* A2  = (const float*)d_in[15];
  const float* ab2 = (const float*)d_in[16];
  const float* ag2 = (const float*)d_in[17];
  const float* abt2= (const float*)d_in[18];

  char* ws = (char*)d_ws;
  size_t off = 0;
  auto alloc = [&](size_t bytes){ size_t o = off; off = (off + bytes + 255) & ~(size_t)255; return o; };
  // partials (12.6 MB) aliases geom (2 MB): lifetimes are disjoint on the
  // serial stream (segsum->segmlp complete before knn writes geom).
  char*           big    = ws + alloc((size_t)4*16*64*768*4);
  float*          partials = (float*)big;
  float*          geom     = (float*)big;
  unsigned short* hprime = (unsigned short*)(ws + alloc((size_t)16384*64*2));
  float*          S1w    = (float*)(ws + alloc(16384*4));
  float*          S2w    = (float*)(ws + alloc(16384*4));
  unsigned short* W2T    = (unsigned short*)(ws + alloc(768*64*2));
  unsigned short* Gm     = (unsigned short*)(ws + alloc(64*64*2));
  float*          w2bar  = (float*)(ws + alloc(64*4));
  float*          ubar   = (float*)(ws + alloc(64*4));
  float*          scal   = (float*)(ws + alloc(2*4));
  float*          cntp   = (float*)(ws + alloc(4*16*64*4));
  float*          cntw   = (float*)(ws + alloc(4*64*4));
  float*          agg    = (float*)(ws + alloc((size_t)4*64*768*4));

  k_prep  <<<dim3(113), dim3(256), 0, stream>>>(W2, b2, Gm, w2bar, ubar, scal, W2T);
  k_segsum<<<dim3(192), dim3(256), 0, stream>>>(features, labels, partials, cntp);
  k_segmlp<<<dim3(256), dim3(256), 0, stream>>>(partials, cntp, A1, ab1, ag1, abt1,
                                                A2, ab2, ag2, abt2, agg, cntw);
  k_knn   <<<dim3(256), dim3(1024),0, stream>>>(coords, geom);
  k_hbuild<<<dim3(512), dim3(256), 0, stream>>>(geom, W1, b1, g1, bt1, Gm, w2bar, ubar, scal,
                                                hprime, S1w, S2w);
  k_final <<<dim3(256), dim3(256), 0, stream>>>(hprime, W2T, S1w, S2w, g2, b2, bt2,
                                                features, labels, cntw, agg, (float*)d_out);
}